// Round 1
// baseline (105.293 us; speedup 1.0000x reference)
//
#include <hip/hip_runtime.h>
#include <hip/hip_bf16.h>
#include <stdint.h>

#define BB   8
#define LL   1024
#define LOO  1024
#define HH   768
#define VV   4096
#define OUTW 5120   // VV + LL

typedef unsigned short ushort_t;
typedef __attribute__((ext_vector_type(4))) float   f32x4;
typedef __attribute__((ext_vector_type(8))) __bf16  bf16x8;
typedef __attribute__((ext_vector_type(4))) float   float4v;
typedef __attribute__((ext_vector_type(4))) unsigned short ushort4v;

static __device__ __forceinline__ ushort_t f2bf(float f) {
    union { float f; uint32_t u; } v; v.f = f;
    uint32_t u = v.u;
    uint32_t r = (u + 0x7fffu + ((u >> 16) & 1u)) >> 16;
    return (ushort_t)r;
}

// ---------------- segment scan: 1 block per batch ----------------
__global__ void seg_kernel(const int* __restrict__ tags,
                           int* __restrict__ seg_start,   // [BB][LL+1]
                           int* __restrict__ emitted) {   // [BB]
    int b = blockIdx.x;
    int p = threadIdx.x;                // 0..1023
    const int* t = tags + b * LL;
    int myTag = t[p];
    int isStart = (p == 0) || (myTag != t[p - 1]);
    __shared__ int sc[LL];
    sc[p] = isStart;
    __syncthreads();
    for (int off = 1; off < LL; off <<= 1) {
        int v   = sc[p];
        int add = (p >= off) ? sc[p - off] : 0;
        __syncthreads();
        sc[p] = v + add;
        __syncthreads();
    }
    int incl = sc[p];                   // inclusive scan of starts
    if (isStart) seg_start[b * (LL + 1) + (incl - 1)] = p;
    if (p == LL - 1) {
        emitted[b] = incl - 1;          // total_runs - 1 (last run dropped)
        seg_start[b * (LL + 1) + incl] = LL;
    }
}

// ---------------- segment means -> bf16 attn [BB][LL][HH] ----------------
__global__ void attn_kernel(const float* __restrict__ h1,
                            const int* __restrict__ seg_start,
                            const int* __restrict__ emitted,
                            ushort_t* __restrict__ attn) {
    int b = blockIdx.x >> 10;
    int r = blockIdx.x & 1023;
    int em = emitted[b];
    ushort_t* arow = attn + ((size_t)b * LL + r) * HH;
    int tid = threadIdx.x;              // 256 threads, 3 cols each
    if (r >= em) {
        arow[tid] = 0; arow[tid + 256] = 0; arow[tid + 512] = 0;
        return;
    }
    const int* ss = seg_start + b * (LL + 1);
    int s = ss[r], e = ss[r + 1];
    float inv = 1.0f / (float)(e - s);
    const float* hb = h1 + (size_t)b * LL * HH;
    float a0 = 0.f, a1 = 0.f, a2 = 0.f;
    for (int p = s; p < e; ++p) {
        const float* row = hb + (size_t)p * HH;
        a0 += row[tid]; a1 += row[tid + 256]; a2 += row[tid + 512];
    }
    arow[tid]       = f2bf(a0 * inv);
    arow[tid + 256] = f2bf(a1 * inv);
    arow[tid + 512] = f2bf(a2 * inv);
}

// ---------------- cast hidden2 f32 -> bf16 ----------------
__global__ void cast_h2_kernel(const float* __restrict__ h2,
                               ushort_t* __restrict__ h2b) {
    int i = blockIdx.x * blockDim.x + threadIdx.x;   // 0 .. BB*LOO*HH/4-1
    float4v v = ((const float4v*)h2)[i];
    ushort4v o;
    o[0] = f2bf(v[0]); o[1] = f2bf(v[1]); o[2] = f2bf(v[2]); o[3] = f2bf(v[3]);
    ((ushort4v*)h2b)[i] = o;
}

// ---------------- copy lm_logits into out[:, :, 0:V] ----------------
__global__ void copy_logits_kernel(const float* __restrict__ lm,
                                   float* __restrict__ out) {
    const float4v* in4 = (const float4v*)lm;
    float4v* out4 = (float4v*)out;
    const size_t total = (size_t)BB * LOO * (VV / 4);   // 8388608
    for (size_t i = (size_t)blockIdx.x * blockDim.x + threadIdx.x;
         i < total; i += (size_t)gridDim.x * blockDim.x) {
        size_t row = i >> 10;          // VV/4 = 1024 float4 per row
        size_t col = i & 1023;
        out4[row * (OUTW / 4) + col] = in4[i];
    }
}

// ---------------- batched NT bf16 GEMM + bias epilogue ----------------
// C[b][o][l] = sum_h A[b][o][h] * Bm[b][l][h]  + (l<em ? 0 : -100)
// grid = BB * 8 * 8 blocks of 256 threads; 128x128 tile, BK=64.
__global__ __launch_bounds__(256, 2) void gemm_kernel(
        const ushort_t* __restrict__ A,    // h2 bf16 [BB][LOO][HH]
        const ushort_t* __restrict__ Bm,   // attn bf16 [BB][LL][HH]
        const int* __restrict__ emitted,
        float* __restrict__ out) {
    __shared__ char smem[32768];          // A tile @0 (16KB), B tile @16384

    int bid  = blockIdx.x;
    int b    = bid >> 6;
    int t2   = bid & 63;
    int brow = (t2 >> 3) << 7;
    int bcol = (t2 & 7) << 7;

    const int tid  = threadIdx.x;
    const int lane = tid & 63;
    const int wid  = tid >> 6;
    const int wr   = (wid >> 1) & 1;
    const int wc   = wid & 1;

    const ushort_t* Ab = A  + (size_t)b * LOO * HH;
    const ushort_t* Bb = Bm + (size_t)b * LL * HH;

    f32x4 zero = {0.f, 0.f, 0.f, 0.f};
    f32x4 acc[4][4];
#pragma unroll
    for (int i = 0; i < 4; ++i)
#pragma unroll
        for (int j = 0; j < 4; ++j) acc[i][j] = zero;

    for (int k0 = 0; k0 < HH; k0 += 64) {
        __syncthreads();
        // stage both tiles: 4 issues x 256 threads x 16B each = 16KB per tile.
        // LDS dest is linear; global source column is pre-XOR-swizzled so that
        // a swizzled ds_read returns correct data (both-sides-or-neither rule).
#pragma unroll
        for (int i = 0; i < 4; ++i) {
            int off = i * 4096 + tid * 16;
            int row = off >> 7;                 // tile row (128B per row)
            int cb  = off & 127;                // byte within row
            int scb = cb ^ ((row & 7) << 4);    // swizzled source column
            const ushort_t* ga = Ab + (size_t)(brow + row) * HH + k0 + (scb >> 1);
            const ushort_t* gb = Bb + (size_t)(bcol + row) * HH + k0 + (scb >> 1);
            __builtin_amdgcn_global_load_lds(
                (const __attribute__((address_space(1))) void*)ga,
                (__attribute__((address_space(3))) void*)(smem + off), 16, 0, 0);
            __builtin_amdgcn_global_load_lds(
                (const __attribute__((address_space(1))) void*)gb,
                (__attribute__((address_space(3))) void*)(smem + 16384 + off), 16, 0, 0);
        }
        asm volatile("s_waitcnt vmcnt(0)" ::: "memory");
        __syncthreads();

#pragma unroll
        for (int ks = 0; ks < 2; ++ks) {
            bf16x8 af[4], bfr[4];
#pragma unroll
            for (int mi = 0; mi < 4; ++mi) {
                int row  = (wr << 6) + (mi << 4) + (lane & 15);
                int colb = (ks << 6) + ((lane >> 4) << 4);
                int addr = (row << 7) + (colb ^ ((row & 7) << 4));
                af[mi] = *(const bf16x8*)(smem + addr);
            }
#pragma unroll
            for (int ni = 0; ni < 4; ++ni) {
                int row  = (wc << 6) + (ni << 4) + (lane & 15);
                int colb = (ks << 6) + ((lane >> 4) << 4);
                int addr = (row << 7) + (colb ^ ((row & 7) << 4));
                bfr[ni] = *(const bf16x8*)(smem + 16384 + addr);
            }
#pragma unroll
            for (int mi = 0; mi < 4; ++mi)
#pragma unroll
                for (int ni = 0; ni < 4; ++ni)
                    acc[mi][ni] = __builtin_amdgcn_mfma_f32_16x16x32_bf16(
                        af[mi], bfr[ni], acc[mi][ni], 0, 0, 0);
        }
    }

    // epilogue: C/D layout col=lane&15, row=(lane>>4)*4+reg (m89-verified)
    int em = emitted[b];
    float* outb = out + (size_t)b * LOO * OUTW + VV;
#pragma unroll
    for (int mi = 0; mi < 4; ++mi) {
        int rbase = brow + (wr << 6) + (mi << 4) + ((lane >> 4) << 2);
#pragma unroll
        for (int ni = 0; ni < 4; ++ni) {
            int col = bcol + (wc << 6) + (ni << 4) + (lane & 15);
            float badd = (col < em) ? 0.0f : -100.0f;
#pragma unroll
            for (int rr = 0; rr < 4; ++rr)
                outb[(size_t)(rbase + rr) * OUTW + col] = acc[mi][ni][rr] + badd;
        }
    }
}

extern "C" void kernel_launch(void* const* d_in, const int* in_sizes, int n_in,
                              void* d_out, int out_size, void* d_ws, size_t ws_size,
                              hipStream_t stream) {
    const float* h1   = (const float*)d_in[0];   // [8,1024,768]
    const float* h2   = (const float*)d_in[1];   // [8,1024,768]
    const float* lm   = (const float*)d_in[2];   // [8,1024,4096]
    const int*   tags = (const int*)d_in[3];     // [8,1024]
    float* out = (float*)d_out;                  // [8,1024,5120]

    // workspace layout (25.2 MB total)
    char* ws = (char*)d_ws;
    ushort_t* h2b      = (ushort_t*)ws;                          // 12,582,912 B
    ushort_t* attn     = (ushort_t*)(ws + 12582912);             // 12,582,912 B
    int*      seg_strt = (int*)(ws + 25165824);                  // 8*1025*4 B
    int*      emitted  = (int*)(ws + 25165824 + 32800);          // 32 B

    seg_kernel<<<BB, LL, 0, stream>>>(tags, seg_strt, emitted);
    attn_kernel<<<BB * LL, 256, 0, stream>>>(h1, seg_strt, emitted, attn);
    cast_h2_kernel<<<(BB * LOO * HH / 4) / 256, 256, 0, stream>>>(h2, h2b);
    copy_logits_kernel<<<4096, 256, 0, stream>>>(lm, out);
    gemm_kernel<<<BB * 64, 256, 0, stream>>>(h2b, attn, emitted, out);
}

// Round 2
// 95.375 us; speedup vs baseline: 1.1040x; 1.1040x over previous
//
#include <hip/hip_runtime.h>
#include <hip/hip_bf16.h>
#include <stdint.h>

#define BB   8
#define LL   1024
#define LOO  1024
#define HH   768
#define VV   4096
#define OUTW 5120   // VV + LL
#define EMAX 256    // tags sorted from [0,256) => emitted <= 255

typedef unsigned short ushort_t;
typedef __attribute__((ext_vector_type(4))) float   f32x4;
typedef __attribute__((ext_vector_type(8))) __bf16  bf16x8;
typedef __attribute__((ext_vector_type(4))) float   float4v;
typedef __attribute__((ext_vector_type(4))) unsigned short ushort4v;

static __device__ __forceinline__ ushort_t f2bf(float f) {
    union { float f; uint32_t u; } v; v.f = f;
    uint32_t u = v.u;
    uint32_t r = (u + 0x7fffu + ((u >> 16) & 1u)) >> 16;
    return (ushort_t)r;
}

// ---------------- segment scan: 1 block per batch ----------------
__global__ void seg_kernel(const int* __restrict__ tags,
                           int* __restrict__ seg_start,   // [BB][LL+1]
                           int* __restrict__ emitted) {   // [BB]
    int b = blockIdx.x;
    int p = threadIdx.x;                // 0..1023
    const int* t = tags + b * LL;
    int myTag = t[p];
    int isStart = (p == 0) || (myTag != t[p - 1]);
    __shared__ int sc[LL];
    sc[p] = isStart;
    __syncthreads();
    for (int off = 1; off < LL; off <<= 1) {
        int v   = sc[p];
        int add = (p >= off) ? sc[p - off] : 0;
        __syncthreads();
        sc[p] = v + add;
        __syncthreads();
    }
    int incl = sc[p];                   // inclusive scan of starts
    if (isStart) seg_start[b * (LL + 1) + (incl - 1)] = p;
    if (p == LL - 1) {
        emitted[b] = incl - 1;          // total_runs - 1 (last run dropped)
        seg_start[b * (LL + 1) + incl] = LL;
    }
}

// ------------- segment means -> bf16 attn [BB][EMAX][HH] -------------
__global__ void attn_kernel(const float* __restrict__ h1,
                            const int* __restrict__ seg_start,
                            const int* __restrict__ emitted,
                            ushort_t* __restrict__ attn) {
    int b = blockIdx.x >> 8;
    int r = blockIdx.x & 255;           // row 0..255 (cols >=256 are never GEMM'd)
    int em = emitted[b];
    ushort_t* arow = attn + ((size_t)b * EMAX + r) * HH;
    int tid = threadIdx.x;              // 256 threads, 3 cols each
    if (r >= em) {
        arow[tid] = 0; arow[tid + 256] = 0; arow[tid + 512] = 0;
        return;
    }
    const int* ss = seg_start + b * (LL + 1);
    int s = ss[r], e = ss[r + 1];
    float inv = 1.0f / (float)(e - s);
    const float* hb = h1 + (size_t)b * LL * HH;
    float a0 = 0.f, a1 = 0.f, a2 = 0.f;
    for (int p = s; p < e; ++p) {
        const float* row = hb + (size_t)p * HH;
        a0 += row[tid]; a1 += row[tid + 256]; a2 += row[tid + 512];
    }
    arow[tid]       = f2bf(a0 * inv);
    arow[tid + 256] = f2bf(a1 * inv);
    arow[tid + 512] = f2bf(a2 * inv);
}

// ---------------- cast hidden2 f32 -> bf16 ----------------
__global__ void cast_h2_kernel(const float* __restrict__ h2,
                               ushort_t* __restrict__ h2b) {
    int i = blockIdx.x * blockDim.x + threadIdx.x;   // 0 .. BB*LOO*HH/4-1
    float4v v = ((const float4v*)h2)[i];
    ushort4v o;
    o[0] = f2bf(v[0]); o[1] = f2bf(v[1]); o[2] = f2bf(v[2]); o[3] = f2bf(v[3]);
    ((ushort4v*)h2b)[i] = o;
}

// ------------- mega kernel: GEMM blocks + copy/fill blocks -------------
// Blocks [0,128): batched NT bf16 GEMM over out cols [VV, VV+256)
//   C[b][o][l] = sum_h h2[b][o][h]*attn[b][l][h] + (l<em ? 0 : -100)
// Blocks [128, 128+2048): copy lm_logits into out[:,:,0:VV] and fill
//   out[:,:,VV+256 .. VV+LL) with -100. GEMM blocks launch first so their
//   MFMA work overlaps the copy blocks' HBM streaming.
#define NGEMM 128
#define NCOPY 2048
__global__ __launch_bounds__(256, 2) void mega_kernel(
        const ushort_t* __restrict__ A,    // h2 bf16 [BB][LOO][HH]
        const ushort_t* __restrict__ Bm,   // attn bf16 [BB][EMAX][HH]
        const int* __restrict__ emitted,
        const float* __restrict__ lm,
        float* __restrict__ out) {
    __shared__ char smem[32768];          // A tile @0 (16KB), B tile @16384

    if (blockIdx.x >= NGEMM) {
        // ---------------- copy + fill path ----------------
        int cid = blockIdx.x - NGEMM;     // 0..2047
        int tid = threadIdx.x;
        const float4v* in4 = (const float4v*)lm;
        float4v* out4 = (float4v*)out;
        int c = cid * 256 + tid;          // 0..524287
        // copy: 8M float4, 16 per thread, grouped 4 for outstanding loads
#pragma unroll
        for (int g = 0; g < 4; ++g) {
            size_t i0 = (size_t)(g * 4 + 0) * 524288 + c;
            size_t i1 = (size_t)(g * 4 + 1) * 524288 + c;
            size_t i2 = (size_t)(g * 4 + 2) * 524288 + c;
            size_t i3 = (size_t)(g * 4 + 3) * 524288 + c;
            float4v v0 = in4[i0];
            float4v v1 = in4[i1];
            float4v v2 = in4[i2];
            float4v v3 = in4[i3];
            out4[i0 + ((i0 >> 10) << 8)] = v0;   // out_idx = i + row*256
            out4[i1 + ((i1 >> 10) << 8)] = v1;
            out4[i2 + ((i2 >> 10) << 8)] = v2;
            out4[i3 + ((i3 >> 10) << 8)] = v3;
        }
        // fill out cols [VV+256, VV+1024) with -100: 192 float4/row, 4 rows/blk
        float4v fv = {-100.f, -100.f, -100.f, -100.f};
        if (tid < 192) {
#pragma unroll
            for (int j = 0; j < 4; ++j) {
                size_t row = (size_t)cid * 4 + j;      // 0..8191
                out4[row * (OUTW / 4) + (VV + 256) / 4 + tid] = fv;
            }
        }
        return;
    }

    // ---------------- GEMM path ----------------
    int bid  = blockIdx.x;
    int b    = bid >> 4;
    int t2   = bid & 15;
    int brow = (t2 >> 1) << 7;            // 0..896
    int bcol = (t2 & 1) << 7;             // 0 or 128

    const int tid  = threadIdx.x;
    const int lane = tid & 63;
    const int wid  = tid >> 6;
    const int wr   = (wid >> 1) & 1;
    const int wc   = wid & 1;

    const ushort_t* Ab = A  + (size_t)b * LOO * HH;
    const ushort_t* Bb = Bm + (size_t)b * EMAX * HH;

    f32x4 zero = {0.f, 0.f, 0.f, 0.f};
    f32x4 acc[4][4];
#pragma unroll
    for (int i = 0; i < 4; ++i)
#pragma unroll
        for (int j = 0; j < 4; ++j) acc[i][j] = zero;

    for (int k0 = 0; k0 < HH; k0 += 64) {
        __syncthreads();
        // stage both tiles; LDS dest linear, global source col pre-XOR-swizzled
        // (both-sides-or-neither rule, guide G4/T2)
#pragma unroll
        for (int i = 0; i < 4; ++i) {
            int off = i * 4096 + tid * 16;
            int row = off >> 7;                 // tile row (128B per row)
            int cb  = off & 127;                // byte within row
            int scb = cb ^ ((row & 7) << 4);    // swizzled source column
            const ushort_t* ga = Ab + (size_t)(brow + row) * HH + k0 + (scb >> 1);
            const ushort_t* gb = Bb + (size_t)(bcol + row) * HH + k0 + (scb >> 1);
            __builtin_amdgcn_global_load_lds(
                (const __attribute__((address_space(1))) void*)ga,
                (__attribute__((address_space(3))) void*)(smem + off), 16, 0, 0);
            __builtin_amdgcn_global_load_lds(
                (const __attribute__((address_space(1))) void*)gb,
                (__attribute__((address_space(3))) void*)(smem + 16384 + off), 16, 0, 0);
        }
        asm volatile("s_waitcnt vmcnt(0)" ::: "memory");
        __syncthreads();

#pragma unroll
        for (int ks = 0; ks < 2; ++ks) {
            bf16x8 af[4], bfr[4];
#pragma unroll
            for (int mi = 0; mi < 4; ++mi) {
                int row  = (wr << 6) + (mi << 4) + (lane & 15);
                int colb = (ks << 6) + ((lane >> 4) << 4);
                int addr = (row << 7) + (colb ^ ((row & 7) << 4));
                af[mi] = *(const bf16x8*)(smem + addr);
            }
#pragma unroll
            for (int ni = 0; ni < 4; ++ni) {
                int row  = (wc << 6) + (ni << 4) + (lane & 15);
                int colb = (ks << 6) + ((lane >> 4) << 4);
                int addr = (row << 7) + (colb ^ ((row & 7) << 4));
                bfr[ni] = *(const bf16x8*)(smem + 16384 + addr);
            }
#pragma unroll
            for (int mi = 0; mi < 4; ++mi)
#pragma unroll
                for (int ni = 0; ni < 4; ++ni)
                    acc[mi][ni] = __builtin_amdgcn_mfma_f32_16x16x32_bf16(
                        af[mi], bfr[ni], acc[mi][ni], 0, 0, 0);
        }
    }

    // epilogue: C/D layout col=lane&15, row=(lane>>4)*4+reg (m89-verified)
    int em = emitted[b];
    float* outb = out + (size_t)b * LOO * OUTW + VV;
#pragma unroll
    for (int mi = 0; mi < 4; ++mi) {
        int rbase = brow + (wr << 6) + (mi << 4) + ((lane >> 4) << 2);
#pragma unroll
        for (int ni = 0; ni < 4; ++ni) {
            int col = bcol + (wc << 6) + (ni << 4) + (lane & 15);
            float badd = (col < em) ? 0.0f : -100.0f;
#pragma unroll
            for (int rr = 0; rr < 4; ++rr)
                outb[(size_t)(rbase + rr) * OUTW + col] = acc[mi][ni][rr] + badd;
        }
    }
}

extern "C" void kernel_launch(void* const* d_in, const int* in_sizes, int n_in,
                              void* d_out, int out_size, void* d_ws, size_t ws_size,
                              hipStream_t stream) {
    const float* h1   = (const float*)d_in[0];   // [8,1024,768]
    const float* h2   = (const float*)d_in[1];   // [8,1024,768]
    const float* lm   = (const float*)d_in[2];   // [8,1024,4096]
    const int*   tags = (const int*)d_in[3];     // [8,1024]
    float* out = (float*)d_out;                  // [8,1024,5120]

    // workspace layout (~15.8 MB total)
    char* ws = (char*)d_ws;
    ushort_t* h2b      = (ushort_t*)ws;                          // 12,582,912 B
    ushort_t* attn     = (ushort_t*)(ws + 12582912);             // 3,145,728 B
    int*      seg_strt = (int*)(ws + 12582912 + 3145728);        // 32,800 B
    int*      emitted  = (int*)(ws + 12582912 + 3145728 + 32800);// 32 B

    seg_kernel<<<BB, LL, 0, stream>>>(tags, seg_strt, emitted);
    attn_kernel<<<BB * EMAX, 256, 0, stream>>>(h1, seg_strt, emitted, attn);
    cast_h2_kernel<<<(BB * LOO * HH / 4) / 256, 256, 0, stream>>>(h2, h2b);
    mega_kernel<<<NGEMM + NCOPY, 256, 0, stream>>>(h2b, attn, emitted, lm, out);
}

// Round 3
// 85.078 us; speedup vs baseline: 1.2376x; 1.1210x over previous
//
#include <hip/hip_runtime.h>
#include <hip/hip_bf16.h>
#include <stdint.h>

#define BB   8
#define LL   1024
#define LOO  1024
#define HH   768
#define VV   4096
#define OUTW 5120   // VV + LL
#define EMAX 256    // tags sorted from [0,256) => emitted <= 255

typedef unsigned short ushort_t;
typedef __attribute__((ext_vector_type(4))) float   f32x4;
typedef __attribute__((ext_vector_type(8))) __bf16  bf16x8;
typedef __attribute__((ext_vector_type(4))) float   float4v;
typedef __attribute__((ext_vector_type(4))) int     int4v;

static __device__ __forceinline__ ushort_t f2bf(float f) {
    union { float f; uint32_t u; } v; v.f = f;
    uint32_t u = v.u;
    uint32_t r = (u + 0x7fffu + ((u >> 16) & 1u)) >> 16;
    return (ushort_t)r;
}

// ---- K1: fused tag-scan + segment means -> bf16 attn [BB][EMAX][HH] ----
// One block per (b, r). Each block re-derives run boundaries from the 4KB
// tag row (L2-hot) with a 256-wide scan; removes the seg kernel + dependency.
__global__ __launch_bounds__(256) void attn_fused_kernel(
        const float* __restrict__ h1,
        const int* __restrict__ tags,
        ushort_t* __restrict__ attn,
        int* __restrict__ emitted_out) {
    int b = blockIdx.x >> 8;
    int r = blockIdx.x & 255;
    int tid = threadIdx.x;

    __shared__ int stags[LL];        // 4 KB
    __shared__ int cnt[256];
    __shared__ int runpos[EMAX + 2];

    ((int4v*)stags)[tid] = ((const int4v*)(tags + b * LL))[tid];
    __syncthreads();

    int p0 = tid * 4;
    int st[4];
    int prevm1 = (p0 == 0) ? -2 : stags[p0 - 1];
    st[0] = (p0 == 0) || (stags[p0] != prevm1);
    st[1] = (stags[p0 + 1] != stags[p0]);
    st[2] = (stags[p0 + 2] != stags[p0 + 1]);
    st[3] = (stags[p0 + 3] != stags[p0 + 2]);
    int c = st[0] + st[1] + st[2] + st[3];
    cnt[tid] = c;
    __syncthreads();
    for (int off = 1; off < 256; off <<= 1) {
        int v = cnt[tid];
        int a = (tid >= off) ? cnt[tid - off] : 0;
        __syncthreads();
        cnt[tid] = v + a;
        __syncthreads();
    }
    int total = cnt[255];            // total runs (<= 256, tags sorted)
    int base = cnt[tid] - c;         // exclusive prefix
#pragma unroll
    for (int j = 0; j < 4; ++j)
        if (st[j]) runpos[base++] = p0 + j;
    if (tid == 0) runpos[total] = LL;
    __syncthreads();

    int em = total - 1;              // trailing open run dropped
    if (r == 0 && tid == 0) emitted_out[b] = em;

    ushort_t* arow = attn + ((size_t)b * EMAX + r) * HH;
    if (r >= em) {
        arow[tid] = 0; arow[tid + 256] = 0; arow[tid + 512] = 0;
        return;
    }
    int s = runpos[r], e = runpos[r + 1];
    float inv = 1.0f / (float)(e - s);
    const float* hb = h1 + (size_t)b * LL * HH;
    float a0 = 0.f, a1 = 0.f, a2 = 0.f;
    for (int p = s; p < e; ++p) {
        const float* row = hb + (size_t)p * HH;
        a0 += row[tid]; a1 += row[tid + 256]; a2 += row[tid + 512];
    }
    arow[tid]       = f2bf(a0 * inv);
    arow[tid + 256] = f2bf(a1 * inv);
    arow[tid + 512] = f2bf(a2 * inv);
}

// ------------- K2 mega: GEMM blocks + copy/fill blocks -------------
// Blocks [0,128): batched NT GEMM over out cols [VV, VV+256), A read as f32
//   directly from hidden2 (cvt to bf16 on LDS->reg read — no cast kernel).
// Blocks [128, 128+2048): copy lm_logits into out[:,:,0:VV] and fill
//   out[:,:,VV+256..VV+LL) with -100.
#define NGEMM 128
#define NCOPY 2048
__global__ __launch_bounds__(256, 2) void mega_kernel(
        const float* __restrict__ A,       // h2 f32 [BB][LOO][HH]
        const ushort_t* __restrict__ Bm,   // attn bf16 [BB][EMAX][HH]
        const int* __restrict__ emitted,
        const float* __restrict__ lm,
        float* __restrict__ out) {
    __shared__ char smem[49152];          // A f32 tile 32KB @0, B bf16 16KB @32768

    if (blockIdx.x >= NGEMM) {
        // ---------------- copy + fill path ----------------
        int cid = blockIdx.x - NGEMM;     // 0..2047
        int tid = threadIdx.x;
        const float4v* in4 = (const float4v*)lm;
        float4v* out4 = (float4v*)out;
        int c = cid * 256 + tid;          // 0..524287
#pragma unroll
        for (int g = 0; g < 4; ++g) {
            size_t i0 = (size_t)(g * 4 + 0) * 524288 + c;
            size_t i1 = (size_t)(g * 4 + 1) * 524288 + c;
            size_t i2 = (size_t)(g * 4 + 2) * 524288 + c;
            size_t i3 = (size_t)(g * 4 + 3) * 524288 + c;
            float4v v0 = in4[i0];
            float4v v1 = in4[i1];
            float4v v2 = in4[i2];
            float4v v3 = in4[i3];
            out4[i0 + ((i0 >> 10) << 8)] = v0;   // out_idx = i + row*256
            out4[i1 + ((i1 >> 10) << 8)] = v1;
            out4[i2 + ((i2 >> 10) << 8)] = v2;
            out4[i3 + ((i3 >> 10) << 8)] = v3;
        }
        // fill out cols [VV+256, VV+1024): 192 float4/row, 4 rows/block
        float4v fv = {-100.f, -100.f, -100.f, -100.f};
        if (tid < 192) {
#pragma unroll
            for (int j = 0; j < 4; ++j) {
                size_t row = (size_t)cid * 4 + j;      // 0..8191
                out4[row * (OUTW / 4) + (VV + 256) / 4 + tid] = fv;
            }
        }
        return;
    }

    // ---------------- GEMM path ----------------
    int bid  = blockIdx.x;
    int b    = bid >> 4;
    int t2   = bid & 15;
    int brow = (t2 >> 1) << 7;            // 0..896
    int bcol = (t2 & 1) << 7;             // 0 or 128

    const int tid  = threadIdx.x;
    const int lane = tid & 63;
    const int wid  = tid >> 6;
    const int wr   = (wid >> 1) & 1;
    const int wc   = wid & 1;

    const float*    Ab = A  + (size_t)b * LOO * HH;
    const ushort_t* Bb = Bm + (size_t)b * EMAX * HH;

    f32x4 zero = {0.f, 0.f, 0.f, 0.f};
    f32x4 acc[4][4];
#pragma unroll
    for (int i = 0; i < 4; ++i)
#pragma unroll
        for (int j = 0; j < 4; ++j) acc[i][j] = zero;

    for (int k0 = 0; k0 < HH; k0 += 64) {
        __syncthreads();
        // A tile: 128 rows x 64 f32 = 32KB, row = 256B. Source col pre-XOR-
        // swizzled (granule 32B), LDS dest linear (both-sides-or-neither).
#pragma unroll
        for (int i = 0; i < 8; ++i) {
            int off = i * 4096 + tid * 16;
            int row = off >> 8;                 // 256B per row
            int cb  = off & 255;
            int scb = cb ^ ((row & 7) << 5);
            const float* ga = Ab + (size_t)(brow + row) * HH + k0 + (scb >> 2);
            __builtin_amdgcn_global_load_lds(
                (const __attribute__((address_space(1))) void*)ga,
                (__attribute__((address_space(3))) void*)(smem + off), 16, 0, 0);
        }
        // B tile: 128 rows x 64 bf16 = 16KB, row = 128B, granule 16B.
#pragma unroll
        for (int i = 0; i < 4; ++i) {
            int off = i * 4096 + tid * 16;
            int row = off >> 7;
            int cb  = off & 127;
            int scb = cb ^ ((row & 7) << 4);
            const ushort_t* gb = Bb + (size_t)(bcol + row) * HH + k0 + (scb >> 1);
            __builtin_amdgcn_global_load_lds(
                (const __attribute__((address_space(1))) void*)gb,
                (__attribute__((address_space(3))) void*)(smem + 32768 + off), 16, 0, 0);
        }
        asm volatile("s_waitcnt vmcnt(0)" ::: "memory");
        __syncthreads();

#pragma unroll
        for (int ks = 0; ks < 2; ++ks) {
            bf16x8 af[4], bfr[4];
#pragma unroll
            for (int mi = 0; mi < 4; ++mi) {
                int row  = (wr << 6) + (mi << 4) + (lane & 15);
                int colb = (ks << 7) + ((lane >> 4) << 5);        // f32 bytes
                int addr = (row << 8) + (colb ^ ((row & 7) << 5));
                f32x4 a0 = *(const f32x4*)(smem + addr);
                f32x4 a1 = *(const f32x4*)(smem + addr + 16);
                bf16x8 t;
                t[0] = (__bf16)a0[0]; t[1] = (__bf16)a0[1];
                t[2] = (__bf16)a0[2]; t[3] = (__bf16)a0[3];
                t[4] = (__bf16)a1[0]; t[5] = (__bf16)a1[1];
                t[6] = (__bf16)a1[2]; t[7] = (__bf16)a1[3];
                af[mi] = t;
            }
#pragma unroll
            for (int ni = 0; ni < 4; ++ni) {
                int row  = (wc << 6) + (ni << 4) + (lane & 15);
                int colb = (ks << 6) + ((lane >> 4) << 4);        // bf16 bytes
                int addr = (row << 7) + (colb ^ ((row & 7) << 4));
                bfr[ni] = *(const bf16x8*)(smem + 32768 + addr);
            }
#pragma unroll
            for (int mi = 0; mi < 4; ++mi)
#pragma unroll
                for (int ni = 0; ni < 4; ++ni)
                    acc[mi][ni] = __builtin_amdgcn_mfma_f32_16x16x32_bf16(
                        af[mi], bfr[ni], acc[mi][ni], 0, 0, 0);
        }
    }

    // epilogue: C/D layout col=lane&15, row=(lane>>4)*4+reg (m89-verified)
    int em = emitted[b];
    float* outb = out + (size_t)b * LOO * OUTW + VV;
#pragma unroll
    for (int mi = 0; mi < 4; ++mi) {
        int rbase = brow + (wr << 6) + (mi << 4) + ((lane >> 4) << 2);
#pragma unroll
        for (int ni = 0; ni < 4; ++ni) {
            int col = bcol + (wc << 6) + (ni << 4) + (lane & 15);
            float badd = (col < em) ? 0.0f : -100.0f;
#pragma unroll
            for (int rr = 0; rr < 4; ++rr)
                outb[(size_t)(rbase + rr) * OUTW + col] = acc[mi][ni][rr] + badd;
        }
    }
}

extern "C" void kernel_launch(void* const* d_in, const int* in_sizes, int n_in,
                              void* d_out, int out_size, void* d_ws, size_t ws_size,
                              hipStream_t stream) {
    const float* h1   = (const float*)d_in[0];   // [8,1024,768]
    const float* h2   = (const float*)d_in[1];   // [8,1024,768]
    const float* lm   = (const float*)d_in[2];   // [8,1024,4096]
    const int*   tags = (const int*)d_in[3];     // [8,1024]
    float* out = (float*)d_out;                  // [8,1024,5120]

    // workspace: attn bf16 [8][256][768] + emitted[8]
    char* ws = (char*)d_ws;
    ushort_t* attn    = (ushort_t*)ws;                 // 3,145,728 B
    int*      emitted = (int*)(ws + 3145728);          // 32 B

    attn_fused_kernel<<<BB * EMAX, 256, 0, stream>>>(h1, tags, attn, emitted);
    mega_kernel<<<NGEMM + NCOPY, 256, 0, stream>>>(h2, attn, emitted, lm, out);
}